// Round 5
// baseline (347.909 us; speedup 1.0000x reference)
//
#include <hip/hip_runtime.h>

// Fused 2-layer GRU, round 17: self-sufficient waves -- no intra-layer exchange.
// S=256, B=8192, IN=1, H=32, L=2.
//
// 512 blocks x 128 thr (2 waves). Block owns 16 batch cols; w0 = layer 0,
// w1 = layer 1 (lag 1 step). Each wave computes ALL 32 h-rows for its 16
// cols via two M-half MFMAs per gate (rows 0-15 and 16-31), so the next
// step's B-fragment is rebuilt from the wave's OWN LDS writes (lgkm-ordered,
// NO barrier on the recurrence critical path). The single barrier per step
// only publishes h0(i) to the L1 wave (lag-1 producer->consumer, 2-deep ring).
//
// Removes the R12-R16 bottleneck: the post-barrier ds_read latency + 4-wave
// lockstep that caused the measured ~34% per-iteration bubble.
//
// Gate math (R13, verified): merged-rcp combine, 5 trans/elem:
//   h' = [Nx*Nz - 2*Ez + (h-1)*Nx] * rcp(Nx*Nz);  hm = h-1 in registers.

#define S_LEN 256
#define B_SZ  8192
#define H_SZ  32
#define RS    40     // LDS col stride in shorts (80 B): 32 rows + pad

typedef __attribute__((ext_vector_type(8))) short short8;  // 8 bf16
typedef __attribute__((ext_vector_type(4))) float f32x4;   // MFMA C/D

#define MFMA(a, b, c) __builtin_amdgcn_mfma_f32_16x16x32_bf16(a, b, c, 0, 0, 0)

__device__ __forceinline__ unsigned short bf_rne1(float f) {
    union { float f; unsigned u; } x; x.f = f;
    unsigned u = x.u + 0x7fffu + ((x.u >> 16) & 1u);
    return (unsigned short)(u >> 16);
}

#if __has_builtin(__builtin_amdgcn_cvt_pk_bf16_f32)
typedef __bf16 bf16x2 __attribute__((ext_vector_type(2)));
__device__ __forceinline__ unsigned pk2(float a, float b) {
    union { bf16x2 v; unsigned u; } c;
    c.v = __builtin_amdgcn_cvt_pk_bf16_f32(a, b);
    return c.u;
}
#else
__device__ __forceinline__ unsigned pk2(float a, float b) {
    return (unsigned)bf_rne1(a) | ((unsigned)bf_rne1(b) << 16);
}
#endif

union Frag8 { short8 s8; unsigned u[4]; };

// Merged-rcp GRU combine on one 4-element accumulator quad.
// Dr,Dz carry -log2e*(preact); Dn,Dxn carry 2log2e*(hh / ih parts of n).
// hm[r] = h-1 (updated in place). Returns the two packed-bf16 words.
__device__ __forceinline__ uint2 gru_combine(const f32x4& Dr, const f32x4& Dz,
                                             const f32x4& Dn, const f32x4& Dxn,
                                             float* hm) {
    float v4[4];
#pragma unroll
    for (int r = 0; r < 4; ++r) {
        const float Er = __builtin_amdgcn_exp2f(Dr[r]);
        const float rg = __builtin_amdgcn_rcpf(1.0f + Er);           // r gate
        const float X  = __builtin_amdgcn_exp2f(fmaf(rg, Dn[r], Dxn[r]));
        const float Ez = __builtin_amdgcn_exp2f(Dz[r]);
        const float Nx = 1.0f + X;            // tanh denom
        const float Nz = 1.0f + Ez;           // z denom
        const float P  = Nx * Nz;
        float num = fmaf(-2.0f, Ez, P);       // Nx*Nz - 2*Ez
        num = fmaf(hm[r], Nx, num);           // + (h-1)*Nx
        const float v = num * __builtin_amdgcn_rcpf(P);
        hm[r] = v - 1.0f;
        v4[r] = v;
    }
    return make_uint2(pk2(v4[0], v4[1]), pk2(v4[2], v4[3]));
}

__global__ __launch_bounds__(128, 1) void gru_xm(
    const float* __restrict__ x,      // (S,B,1)
    const float* __restrict__ h_in,   // (2,B,H)
    const float* __restrict__ W_ih0,  // (96,1)
    const float* __restrict__ W_hh0,  // (96,32)
    const float* __restrict__ b_ih0,  // (96)
    const float* __restrict__ b_hh0,  // (96)
    const float* __restrict__ W_ih1,  // (96,32)
    const float* __restrict__ W_hh1,  // (96,32)
    const float* __restrict__ b_ih1,  // (96)
    const float* __restrict__ b_hh1,  // (96)
    const float* __restrict__ W_out,  // (1,32)
    const float* __restrict__ b_out,  // (1)
    float* __restrict__ out)          // y (S*B) then h_state (2,B,H)
{
    // col-major h tiles: col n at n*RS shorts, row r at +r. 80 B stride.
    __shared__ __align__(16) unsigned short ring0[2][16 * RS];  // h0: L0 -> L1
    __shared__ __align__(16) unsigned short scr1[16 * RS];      // h1: L1-private
    __shared__ __align__(16) float sx[(S_LEN + 1) * 16];        // staged x (+pad)
    __shared__ __align__(16) float sy[S_LEN * 16];              // buffered y

    const int tid  = threadIdx.x;
    const int role = tid >> 6;        // 0 = layer 0, 1 = layer 1
    const int lane = tid & 63;
    const int n    = lane & 15;       // batch col within block
    const int q    = lane >> 4;       // quad: k-slots 8q..8q+7 / rows 4q..4q+3
    const int base = blockIdx.x * 16;
    const int bn   = base + n;

    // ---- stage x (coalesced float4, both waves) ----
    for (int s = tid; s < S_LEN * 4; s += 128) {
        const int t = s >> 2, c = s & 3;
        *(float4*)&sx[t * 16 + c * 4] = *(const float4*)&x[t * B_SZ + base + c * 4];
    }

    const float SRZ = -1.4426950408889634f;  // -log2(e)   (sigmoid gates)
    const float SN  =  2.8853900817779268f;  //  2*log2(e) (tanh gate)

    // ---- per-role persistent weights: idx = 2*gate + mhalf ----
    short8 A_h[6], A_i[6];            // recurrent / (L1 ih | L0 one-col x)
    f32x4  C_h[6], C_i3[2];
    short8 Awo = {0, 0, 0, 0, 0, 0, 0, 0};        // y head A-frag (wave 1)
    short8 Bx  = {0, 0, 0, 0, 0, 0, 0, 0};        // x B-frag (wave 0), k=0 slot
    float  hm0[4], hm1[4];            // h-1 for rows 4q..4q+3 / 16+4q..16+4q+3

    if (role == 0) {
#pragma unroll
        for (int t = 0; t < 3; ++t) {
            const float sc = (t < 2) ? SRZ : SN;
#pragma unroll
            for (int m = 0; m < 2; ++m) {
                const int idx = 2 * t + m;
                const int row = 32 * t + 16 * m + n;
#pragma unroll
                for (int e = 0; e < 8; ++e) {
                    A_h[idx][e] = (short)bf_rne1(W_hh0[row * H_SZ + q * 8 + e] * sc);
                    A_i[idx][e] = (q == 0 && e == 0)
                                  ? (short)bf_rne1(W_ih0[row] * sc) : (short)0;
                }
#pragma unroll
                for (int r = 0; r < 4; ++r) {
                    const int gr = 32 * t + 16 * m + 4 * q + r;
                    C_h[idx][r] = (t < 2) ? SRZ * (b_ih0[gr] + b_hh0[gr])
                                          : SN * b_hh0[gr];
                    if (t == 2) C_i3[m][r] = SN * b_ih0[gr];
                }
            }
        }
#pragma unroll
        for (int r = 0; r < 4; ++r) {
            hm0[r] = h_in[bn * H_SZ + 4 * q + r] - 1.0f;
            hm1[r] = h_in[bn * H_SZ + 16 + 4 * q + r] - 1.0f;
        }
    } else {
#pragma unroll
        for (int t = 0; t < 3; ++t) {
            const float sc = (t < 2) ? SRZ : SN;
#pragma unroll
            for (int m = 0; m < 2; ++m) {
                const int idx = 2 * t + m;
                const int row = 32 * t + 16 * m + n;
#pragma unroll
                for (int e = 0; e < 8; ++e) {
                    A_h[idx][e] = (short)bf_rne1(W_hh1[row * H_SZ + q * 8 + e] * sc);
                    A_i[idx][e] = (short)bf_rne1(W_ih1[row * H_SZ + q * 8 + e] * sc);
                }
#pragma unroll
                for (int r = 0; r < 4; ++r) {
                    const int gr = 32 * t + 16 * m + 4 * q + r;
                    C_h[idx][r] = (t < 2) ? SRZ * (b_ih1[gr] + b_hh1[gr])
                                          : SN * b_hh1[gr];
                    if (t == 2) C_i3[m][r] = SN * b_ih1[gr];
                }
            }
        }
#pragma unroll
        for (int r = 0; r < 4; ++r) {
            hm0[r] = h_in[B_SZ * H_SZ + bn * H_SZ + 4 * q + r] - 1.0f;
            hm1[r] = h_in[B_SZ * H_SZ + bn * H_SZ + 16 + 4 * q + r] - 1.0f;
        }
#pragma unroll
        for (int e = 0; e < 8; ++e)                 // all rows = W_out
            Awo[e] = (short)bf_rne1(W_out[q * 8 + e]);
    }
    const f32x4 Z4 = {0.f, 0.f, 0.f, 0.f};
    const float bout = b_out[0];

    // ---- initial own-h B fragment straight from h_in (k = 8q..8q+7) ----
    short8 Bown;
    {
        const float* hsrc = h_in + (size_t)role * B_SZ * H_SZ + (size_t)bn * H_SZ + 8 * q;
        Frag8 f;
        const float4 a = *(const float4*)&hsrc[0];
        const float4 b = *(const float4*)&hsrc[4];
        f.u[0] = pk2(a.x, a.y); f.u[1] = pk2(a.z, a.w);
        f.u[2] = pk2(b.x, b.y); f.u[3] = pk2(b.z, b.w);
        Bown = f.s8;
    }

    const int wr0 = n * RS + 4 * q;        // rows 4q..4q+3   (m=0), uint2
    const int wr1 = n * RS + 16 + 4 * q;   // rows 16+4q..+3  (m=1), uint2
    const int rd  = n * RS + 8 * q;        // k = 8q..8q+7, b128

    __syncthreads();   // x staged
    float xc = sx[n];

    // ================= iter 0 (peeled): L0 computes h0(0) =================
    if (role == 0) {
        Frag8 bxu; bxu.s8 = Bx; bxu.u[0] = pk2(xc, xc); Bx = bxu.s8;
        f32x4 Dr0 = MFMA(A_h[0], Bown, C_h[0]); Dr0 = MFMA(A_i[0], Bx, Dr0);
        f32x4 Dr1 = MFMA(A_h[1], Bown, C_h[1]); Dr1 = MFMA(A_i[1], Bx, Dr1);
        f32x4 Dz0 = MFMA(A_h[2], Bown, C_h[2]); Dz0 = MFMA(A_i[2], Bx, Dz0);
        f32x4 Dz1 = MFMA(A_h[3], Bown, C_h[3]); Dz1 = MFMA(A_i[3], Bx, Dz1);
        f32x4 Dn0 = MFMA(A_h[4], Bown, C_h[4]);
        f32x4 Dn1 = MFMA(A_h[5], Bown, C_h[5]);
        f32x4 Dx0 = MFMA(A_i[4], Bx, C_i3[0]);
        f32x4 Dx1 = MFMA(A_i[5], Bx, C_i3[1]);
        *(uint2*)&ring0[0][wr0] = gru_combine(Dr0, Dz0, Dn0, Dx0, hm0);
        *(uint2*)&ring0[0][wr1] = gru_combine(Dr1, Dz1, Dn1, Dx1, hm1);
        Bown = *(const short8*)&ring0[0][rd];   // own h0(0), lgkm-ordered
        xc = sx[16 + n];                        // x(1)
    }
    __syncthreads();   // publish ring0[0] = h0(0) to L1

    // ================= hot loop i = 1 .. S-1 ===============================
#pragma unroll 2
    for (int i = 1; i < S_LEN; ++i) {
        if (role == 0) {
            // h0(i) from own Bown = h0(i-1): barrier-free recurrence.
            const int buf = i & 1;
            Frag8 bxu; bxu.s8 = Bx; bxu.u[0] = pk2(xc, xc); Bx = bxu.s8;
            f32x4 Dr0 = MFMA(A_h[0], Bown, C_h[0]); Dr0 = MFMA(A_i[0], Bx, Dr0);
            f32x4 Dr1 = MFMA(A_h[1], Bown, C_h[1]); Dr1 = MFMA(A_i[1], Bx, Dr1);
            f32x4 Dz0 = MFMA(A_h[2], Bown, C_h[2]); Dz0 = MFMA(A_i[2], Bx, Dz0);
            f32x4 Dz1 = MFMA(A_h[3], Bown, C_h[3]); Dz1 = MFMA(A_i[3], Bx, Dz1);
            f32x4 Dn0 = MFMA(A_h[4], Bown, C_h[4]);
            f32x4 Dn1 = MFMA(A_h[5], Bown, C_h[5]);
            f32x4 Dx0 = MFMA(A_i[4], Bx, C_i3[0]);
            f32x4 Dx1 = MFMA(A_i[5], Bx, C_i3[1]);
            *(uint2*)&ring0[buf][wr0] = gru_combine(Dr0, Dz0, Dn0, Dx0, hm0);
            *(uint2*)&ring0[buf][wr1] = gru_combine(Dr1, Dz1, Dn1, Dx1, hm1);
            Bown = *(const short8*)&ring0[buf][rd];   // own h0(i)
            xc = sx[(i + 1) * 16 + n];                // prefetch x(i+1)
        } else {
            // h1(i-1) from own Bown = h1(i-2) and h0(i-1) (published i-1).
            const int rb = (i - 1) & 1;
            const short8 B0p = *(const short8*)&ring0[rb][rd];
            f32x4 Gr0 = MFMA(A_h[0], Bown, C_h[0]); Gr0 = MFMA(A_i[0], B0p, Gr0);
            f32x4 Gr1 = MFMA(A_h[1], Bown, C_h[1]); Gr1 = MFMA(A_i[1], B0p, Gr1);
            f32x4 Gz0 = MFMA(A_h[2], Bown, C_h[2]); Gz0 = MFMA(A_i[2], B0p, Gz0);
            f32x4 Gz1 = MFMA(A_h[3], Bown, C_h[3]); Gz1 = MFMA(A_i[3], B0p, Gz1);
            f32x4 Un0 = MFMA(A_h[4], Bown, C_h[4]);
            f32x4 Un1 = MFMA(A_h[5], Bown, C_h[5]);
            f32x4 Vn0 = MFMA(A_i[4], B0p, C_i3[0]);
            f32x4 Vn1 = MFMA(A_i[5], B0p, C_i3[1]);
            *(uint2*)&scr1[wr0] = gru_combine(Gr0, Gz0, Un0, Vn0, hm0);
            *(uint2*)&scr1[wr1] = gru_combine(Gr1, Gz1, Un1, Vn1, hm1);
            Bown = *(const short8*)&scr1[rd];         // own h1(i-1)
            const f32x4 yD = MFMA(Awo, Bown, Z4);     // y(i-1), all rows equal
            if (lane < 16) sy[(i - 1) * 16 + n] = yD[0];
        }
        __syncthreads();   // publish ring0[i&1] = h0(i); guard ring reuse
    }

    // ================= iter S (peeled): L1 computes h1(S-1) ================
    if (role == 1) {
        const int rb = (S_LEN - 1) & 1;
        const short8 B0p = *(const short8*)&ring0[rb][rd];
        f32x4 Gr0 = MFMA(A_h[0], Bown, C_h[0]); Gr0 = MFMA(A_i[0], B0p, Gr0);
        f32x4 Gr1 = MFMA(A_h[1], Bown, C_h[1]); Gr1 = MFMA(A_i[1], B0p, Gr1);
        f32x4 Gz0 = MFMA(A_h[2], Bown, C_h[2]); Gz0 = MFMA(A_i[2], B0p, Gz0);
        f32x4 Gz1 = MFMA(A_h[3], Bown, C_h[3]); Gz1 = MFMA(A_i[3], B0p, Gz1);
        f32x4 Un0 = MFMA(A_h[4], Bown, C_h[4]);
        f32x4 Un1 = MFMA(A_h[5], Bown, C_h[5]);
        f32x4 Vn0 = MFMA(A_i[4], B0p, C_i3[0]);
        f32x4 Vn1 = MFMA(A_i[5], B0p, C_i3[1]);
        *(uint2*)&scr1[wr0] = gru_combine(Gr0, Gz0, Un0, Vn0, hm0);
        *(uint2*)&scr1[wr1] = gru_combine(Gr1, Gz1, Un1, Vn1, hm1);
        Bown = *(const short8*)&scr1[rd];
        const f32x4 yD = MFMA(Awo, Bown, Z4);
        if (lane < 16) sy[(S_LEN - 1) * 16 + n] = yD[0];
    }
    __syncthreads();   // sy complete

    // ---- flush y (coalesced float4 + bias) ----
    for (int s = tid; s < S_LEN * 4; s += 128) {
        const int t = s >> 2, c = s & 3;
        const float4 a = *(const float4*)&sy[t * 16 + c * 4];
        *(float4*)&out[t * B_SZ + base + c * 4] =
            make_float4(a.x + bout, a.y + bout, a.z + bout, a.w + bout);
    }

    // ---- final h_state: out = y (S*B) ++ h0 (B*H) ++ h1 (B*H) ----
    const size_t hoff = (size_t)S_LEN * B_SZ + (size_t)role * B_SZ * H_SZ
                      + (size_t)bn * H_SZ;
    *(float4*)&out[hoff + 4 * q] =
        make_float4(hm0[0] + 1.0f, hm0[1] + 1.0f, hm0[2] + 1.0f, hm0[3] + 1.0f);
    *(float4*)&out[hoff + 16 + 4 * q] =
        make_float4(hm1[0] + 1.0f, hm1[1] + 1.0f, hm1[2] + 1.0f, hm1[3] + 1.0f);
}

extern "C" void kernel_launch(void* const* d_in, const int* in_sizes, int n_in,
                              void* d_out, int out_size, void* d_ws, size_t ws_size,
                              hipStream_t stream) {
    (void)in_sizes; (void)n_in; (void)out_size; (void)d_ws; (void)ws_size;
    const float* x     = (const float*)d_in[0];
    const float* h_in  = (const float*)d_in[1];
    const float* W_ih0 = (const float*)d_in[2];
    const float* W_hh0 = (const float*)d_in[3];
    const float* b_ih0 = (const float*)d_in[4];
    const float* b_hh0 = (const float*)d_in[5];
    const float* W_ih1 = (const float*)d_in[6];
    const float* W_hh1 = (const float*)d_in[7];
    const float* b_ih1 = (const float*)d_in[8];
    const float* b_hh1 = (const float*)d_in[9];
    const float* W_out = (const float*)d_in[10];
    const float* b_out = (const float*)d_in[11];

    dim3 grid(B_SZ / 16);   // 512 blocks x 2 waves = 1024 waves (1/SIMD)
    dim3 block(128);
    gru_xm<<<grid, block, 0, stream>>>(x, h_in, W_ih0, W_hh0, b_ih0, b_hh0,
                                       W_ih1, W_hh1, b_ih1, b_hh1,
                                       W_out, b_out, (float*)d_out);
}

// Round 7
// 329.744 us; speedup vs baseline: 1.0551x; 1.0551x over previous
//
#include <hip/hip_runtime.h>

// Fused 2-layer GRU, round 19: resubmit of R18 (container infra failure, no
// data; audit found no device-side hazard -- same precedent as R14/R15).
// Register-resident recurrence via permuted-A. S=256, B=8192, IN=1, H=32, L=2.
//
// 512 blocks x 128 thr (2 waves). w0 = layer 0, w1 = layer 1 (lag-1).
// THE TRICK: the MFMA output (C/D) layout gives lane(n,q) rows 4q..4q+3 per
// M-half; the next step's B-fragment needs rows 8q..8q+7. We permute the
// WEIGHT ROW ORDER in the A fragments (prow = 8*(n>>2)+(n&3)+4*m, biases +
// hm permuted identically) so M-half-0 delivers h-rows 8q..8q+3 and M-half-1
// delivers 8q+4..8q+7 to each lane. The combine output IS the next B-frag:
// pk2 x4, zero cross-lane traffic. The h-recurrence never touches LDS.
//
// L0->L1 handoff: 16-slot LDS ring of ready-to-read b128 fragments, barrier
// every 8 steps (window double-buffer: L0 writes slots [w&1]*8+j, L1 reads
// the previous window's half; one-ahead ds_read prefetch inside a window).
// y = W_out . h1 via one MFMA per step, stored directly to global.
//
// Gate math (R13, verified): merged-rcp combine, 5 trans/elem:
//   h' = [Nx*Nz - 2*Ez + (h-1)*Nx] * rcp(Nx*Nz);  hm = h-1 in f32 registers.

#define S_LEN 256
#define B_SZ  8192
#define H_SZ  32
#define RS    40            // ring col stride in shorts (80 B)
#define SLOT  (16 * RS)     // shorts per ring slot (16 cols)

typedef __attribute__((ext_vector_type(8))) short short8;  // 8 bf16
typedef __attribute__((ext_vector_type(4))) float f32x4;   // MFMA C/D

#define MFMA(a, b, c) __builtin_amdgcn_mfma_f32_16x16x32_bf16(a, b, c, 0, 0, 0)

__device__ __forceinline__ unsigned short bf_rne1(float f) {
    union { float f; unsigned u; } x; x.f = f;
    unsigned u = x.u + 0x7fffu + ((x.u >> 16) & 1u);
    return (unsigned short)(u >> 16);
}

#if __has_builtin(__builtin_amdgcn_cvt_pk_bf16_f32)
typedef __bf16 bf16x2 __attribute__((ext_vector_type(2)));
__device__ __forceinline__ unsigned pk2(float a, float b) {
    union { bf16x2 v; unsigned u; } c;
    c.v = __builtin_amdgcn_cvt_pk_bf16_f32(a, b);
    return c.u;
}
#else
__device__ __forceinline__ unsigned pk2(float a, float b) {
    return (unsigned)bf_rne1(a) | ((unsigned)bf_rne1(b) << 16);
}
#endif

union Frag8 { short8 s8; unsigned u[4]; };

// Merged-rcp GRU combine on one 4-element quad (3 exp2 + 2 rcp per elem).
// Dr,Dz carry -log2e*(preact); Dn,Dxn carry 2log2e*(hh / ih parts of n).
// hm[r] = h-1 (updated in place). Returns two packed-bf16 words = half of
// the next B-fragment (rows are consecutive thanks to the A permutation).
__device__ __forceinline__ uint2 gru_combine(const f32x4& Dr, const f32x4& Dz,
                                             const f32x4& Dn, const f32x4& Dxn,
                                             float* hm) {
    float v4[4];
#pragma unroll
    for (int r = 0; r < 4; ++r) {
        const float Er = __builtin_amdgcn_exp2f(Dr[r]);
        const float rg = __builtin_amdgcn_rcpf(1.0f + Er);           // r gate
        const float X  = __builtin_amdgcn_exp2f(fmaf(rg, Dn[r], Dxn[r]));
        const float Ez = __builtin_amdgcn_exp2f(Dz[r]);
        const float Nx = 1.0f + X;            // tanh denom
        const float Nz = 1.0f + Ez;           // z denom
        const float P  = Nx * Nz;
        float num = fmaf(-2.0f, Ez, P);       // Nx*Nz - 2*Ez
        num = fmaf(hm[r], Nx, num);           // + (h-1)*Nx
        const float v = num * __builtin_amdgcn_rcpf(P);
        hm[r] = v - 1.0f;
        v4[r] = v;
    }
    return make_uint2(pk2(v4[0], v4[1]), pk2(v4[2], v4[3]));
}

__global__ __launch_bounds__(128) void gru_xm(
    const float* __restrict__ x,      // (S,B,1)
    const float* __restrict__ h_in,   // (2,B,H)
    const float* __restrict__ W_ih0,  // (96,1)
    const float* __restrict__ W_hh0,  // (96,32)
    const float* __restrict__ b_ih0,  // (96)
    const float* __restrict__ b_hh0,  // (96)
    const float* __restrict__ W_ih1,  // (96,32)
    const float* __restrict__ W_hh1,  // (96,32)
    const float* __restrict__ b_ih1,  // (96)
    const float* __restrict__ b_hh1,  // (96)
    const float* __restrict__ W_out,  // (1,32)
    const float* __restrict__ b_out,  // (1)
    float* __restrict__ out)          // y (S*B) then h_state (2,B,H)
{
    __shared__ __align__(16) unsigned short ring[16 * SLOT];   // h0 handoff
    __shared__ __align__(16) float sx[(S_LEN + 1) * 16];       // staged x

    const int tid  = threadIdx.x;
    const int role = tid >> 6;        // 0 = layer 0, 1 = layer 1
    const int lane = tid & 63;
    const int n    = lane & 15;       // batch col / A row
    const int q    = lane >> 4;       // quad: k-slots 8q..8q+7; rows 8q.. after perm
    const int base = blockIdx.x * 16;
    const int bn   = base + n;

    // ---- stage x (coalesced float4, both waves) ----
    for (int s = tid; s < S_LEN * 4; s += 128) {
        const int t = s >> 2, c = s & 3;
        *(float4*)&sx[t * 16 + c * 4] = *(const float4*)&x[t * B_SZ + base + c * 4];
    }

    const float SRZ = -1.4426950408889634f;  // -log2(e)   (sigmoid gates)
    const float SN  =  2.8853900817779268f;  //  2*log2(e) (tanh gate)

    // Permuted weight-row for A row n, M-half m: output row 4q+j -> h-row 8q+j(+4m)
    const int prow = 8 * (n >> 2) + (n & 3);   // + 4*m

    // ---- per-role persistent state: idx = 2*gate + mhalf ----
    short8 A_h[6], A_i[6];            // recurrent / (L1 ih | L0 one-col x)
    f32x4  C_h[6], C_i3[2];
    short8 Awo = {0, 0, 0, 0, 0, 0, 0, 0};        // y head A-frag (wave 1)
    short8 Bx  = {0, 0, 0, 0, 0, 0, 0, 0};        // x B-frag (wave 0), k=0 slot
    float  hm0[4], hm1[4];            // h-1 for rows 8q..8q+3 / 8q+4..8q+7

    if (role == 0) {
#pragma unroll
        for (int t = 0; t < 3; ++t) {
            const float sc = (t < 2) ? SRZ : SN;
#pragma unroll
            for (int m = 0; m < 2; ++m) {
                const int idx = 2 * t + m;
                const int row = 32 * t + prow + 4 * m;   // permuted W row
#pragma unroll
                for (int e = 0; e < 8; ++e) {
                    A_h[idx][e] = (short)bf_rne1(W_hh0[row * H_SZ + q * 8 + e] * sc);
                    A_i[idx][e] = (q == 0 && e == 0)
                                  ? (short)bf_rne1(W_ih0[row] * sc) : (short)0;
                }
#pragma unroll
                for (int r = 0; r < 4; ++r) {
                    const int g = 32 * t + 8 * q + 4 * m + r;   // permuted gate row
                    C_h[idx][r] = (t < 2) ? SRZ * (b_ih0[g] + b_hh0[g])
                                          : SN * b_hh0[g];
                    if (t == 2) C_i3[m][r] = SN * b_ih0[g];
                }
            }
        }
#pragma unroll
        for (int r = 0; r < 4; ++r) {
            hm0[r] = h_in[bn * H_SZ + 8 * q + r] - 1.0f;
            hm1[r] = h_in[bn * H_SZ + 8 * q + 4 + r] - 1.0f;
        }
    } else {
#pragma unroll
        for (int t = 0; t < 3; ++t) {
            const float sc = (t < 2) ? SRZ : SN;
#pragma unroll
            for (int m = 0; m < 2; ++m) {
                const int idx = 2 * t + m;
                const int row = 32 * t + prow + 4 * m;
#pragma unroll
                for (int e = 0; e < 8; ++e) {
                    A_h[idx][e] = (short)bf_rne1(W_hh1[row * H_SZ + q * 8 + e] * sc);
                    A_i[idx][e] = (short)bf_rne1(W_ih1[row * H_SZ + q * 8 + e] * sc);
                }
#pragma unroll
                for (int r = 0; r < 4; ++r) {
                    const int g = 32 * t + 8 * q + 4 * m + r;
                    C_h[idx][r] = (t < 2) ? SRZ * (b_ih1[g] + b_hh1[g])
                                          : SN * b_hh1[g];
                    if (t == 2) C_i3[m][r] = SN * b_ih1[g];
                }
            }
        }
#pragma unroll
        for (int r = 0; r < 4; ++r) {
            hm0[r] = h_in[B_SZ * H_SZ + bn * H_SZ + 8 * q + r] - 1.0f;
            hm1[r] = h_in[B_SZ * H_SZ + bn * H_SZ + 8 * q + 4 + r] - 1.0f;
        }
#pragma unroll
        for (int e = 0; e < 8; ++e)       // all output rows equal: no perm needed
            Awo[e] = (short)bf_rne1(W_out[q * 8 + e]);
    }
    const f32x4 Z4 = {0.f, 0.f, 0.f, 0.f};
    const float bout = b_out[0];

    // ---- initial own-h B fragment from h_in (natural k-order 8q..8q+7) ----
    short8 Bh;   // role0: h0(-1); role1: h1(-1)
    {
        const float* hsrc = h_in + (size_t)role * B_SZ * H_SZ
                          + (size_t)bn * H_SZ + 8 * q;
        Frag8 f;
        const float4 a = *(const float4*)&hsrc[0];
        const float4 b = *(const float4*)&hsrc[4];
        f.u[0] = pk2(a.x, a.y); f.u[1] = pk2(a.z, a.w);
        f.u[2] = pk2(b.x, b.y); f.u[3] = pk2(b.z, b.w);
        Bh = f.s8;
    }

    const int rwoff = n * RS + 8 * q;    // ring b128 offset (shorts), write==read

    __syncthreads();   // x staged
    float xc = sx[n];
    if (role == 0) __builtin_amdgcn_s_setprio(1);   // true-dep chain first

    // ===== window loop: 33 windows of 8 steps; L0 active w<32, L1 w>=1 =====
    for (int win = 0; win < 33; ++win) {
        if (role == 0) {
            if (win < 32) {
                const int sb = (win & 1) * 8;
#pragma unroll 2
                for (int j = 0; j < 8; ++j) {
                    const int t = win * 8 + j;
                    Frag8 bxu; bxu.s8 = Bx; bxu.u[0] = pk2(xc, xc); Bx = bxu.s8;
                    f32x4 Dr0 = MFMA(A_h[0], Bh, C_h[0]); Dr0 = MFMA(A_i[0], Bx, Dr0);
                    f32x4 Dr1 = MFMA(A_h[1], Bh, C_h[1]); Dr1 = MFMA(A_i[1], Bx, Dr1);
                    f32x4 Dz0 = MFMA(A_h[2], Bh, C_h[2]); Dz0 = MFMA(A_i[2], Bx, Dz0);
                    f32x4 Dz1 = MFMA(A_h[3], Bh, C_h[3]); Dz1 = MFMA(A_i[3], Bx, Dz1);
                    f32x4 Dn0 = MFMA(A_h[4], Bh, C_h[4]);
                    f32x4 Dn1 = MFMA(A_h[5], Bh, C_h[5]);
                    f32x4 Dx0 = MFMA(A_i[4], Bx, C_i3[0]);
                    f32x4 Dx1 = MFMA(A_i[5], Bx, C_i3[1]);
                    const uint2 a = gru_combine(Dr0, Dz0, Dn0, Dx0, hm0);
                    const uint2 b = gru_combine(Dr1, Dz1, Dn1, Dx1, hm1);
                    Frag8 nb;
                    nb.u[0] = a.x; nb.u[1] = a.y; nb.u[2] = b.x; nb.u[3] = b.y;
                    Bh = nb.s8;                              // next B: registers!
                    *(short8*)&ring[(sb + j) * SLOT + rwoff] = Bh;  // publish h0(t)
                    xc = sx[(t + 1) * 16 + n];
                }
            }
        } else {
            if (win > 0) {
                const int sb = ((win - 1) & 1) * 8;
                const int t0 = (win - 1) * 8;
                short8 B0p = *(const short8*)&ring[sb * SLOT + rwoff];
#pragma unroll 2
                for (int j = 0; j < 8; ++j) {
                    short8 B0n;
                    if (j < 7)   // one-ahead prefetch (same window: slot is ready)
                        B0n = *(const short8*)&ring[(sb + j + 1) * SLOT + rwoff];
                    f32x4 Gr0 = MFMA(A_h[0], Bh, C_h[0]); Gr0 = MFMA(A_i[0], B0p, Gr0);
                    f32x4 Gr1 = MFMA(A_h[1], Bh, C_h[1]); Gr1 = MFMA(A_i[1], B0p, Gr1);
                    f32x4 Gz0 = MFMA(A_h[2], Bh, C_h[2]); Gz0 = MFMA(A_i[2], B0p, Gz0);
                    f32x4 Gz1 = MFMA(A_h[3], Bh, C_h[3]); Gz1 = MFMA(A_i[3], B0p, Gz1);
                    f32x4 Un0 = MFMA(A_h[4], Bh, C_h[4]);
                    f32x4 Un1 = MFMA(A_h[5], Bh, C_h[5]);
                    f32x4 Vn0 = MFMA(A_i[4], B0p, C_i3[0]);
                    f32x4 Vn1 = MFMA(A_i[5], B0p, C_i3[1]);
                    const uint2 a = gru_combine(Gr0, Gz0, Un0, Vn0, hm0);
                    const uint2 b = gru_combine(Gr1, Gz1, Un1, Vn1, hm1);
                    Frag8 nb;
                    nb.u[0] = a.x; nb.u[1] = a.y; nb.u[2] = b.x; nb.u[3] = b.y;
                    Bh = nb.s8;                              // h1(t0+j)
                    const f32x4 yD = MFMA(Awo, Bh, Z4);      // y(t0+j)
                    if (lane < 16)
                        out[(size_t)(t0 + j) * B_SZ + base + n] = yD[0] + bout;
                    if (j < 7) B0p = B0n;
                }
            }
        }
        __syncthreads();   // window handoff (2-wave barrier, every 8 steps)
    }

    // ---- final h_state: out = y (S*B) ++ h0 (B*H) ++ h1 (B*H) ----
    const size_t hoff = (size_t)S_LEN * B_SZ + (size_t)role * B_SZ * H_SZ
                      + (size_t)bn * H_SZ;
    *(float4*)&out[hoff + 8 * q] =
        make_float4(hm0[0] + 1.0f, hm0[1] + 1.0f, hm0[2] + 1.0f, hm0[3] + 1.0f);
    *(float4*)&out[hoff + 8 * q + 4] =
        make_float4(hm1[0] + 1.0f, hm1[1] + 1.0f, hm1[2] + 1.0f, hm1[3] + 1.0f);
}

extern "C" void kernel_launch(void* const* d_in, const int* in_sizes, int n_in,
                              void* d_out, int out_size, void* d_ws, size_t ws_size,
                              hipStream_t stream) {
    (void)in_sizes; (void)n_in; (void)out_size; (void)d_ws; (void)ws_size;
    const float* x     = (const float*)d_in[0];
    const float* h_in  = (const float*)d_in[1];
    const float* W_ih0 = (const float*)d_in[2];
    const float* W_hh0 = (const float*)d_in[3];
    const float* b_ih0 = (const float*)d_in[4];
    const float* b_hh0 = (const float*)d_in[5];
    const float* W_ih1 = (const float*)d_in[6];
    const float* W_hh1 = (const float*)d_in[7];
    const float* b_ih1 = (const float*)d_in[8];
    const float* b_hh1 = (const float*)d_in[9];
    const float* W_out = (const float*)d_in[10];
    const float* b_out = (const float*)d_in[11];

    dim3 grid(B_SZ / 16);   // 512 blocks x 2 waves = 1024 waves (1/SIMD)
    dim3 block(128);
    gru_xm<<<grid, block, 0, stream>>>(x, h_in, W_ih0, W_hh0, b_ih0, b_hh0,
                                       W_ih1, W_hh1, b_ih1, b_hh1,
                                       W_out, b_out, (float*)d_out);
}

// Round 8
// 237.874 us; speedup vs baseline: 1.4626x; 1.3862x over previous
//
#include <hip/hip_runtime.h>

// Fused 2-layer GRU, round 20: R16 base + critical-path surgery.
// S=256, B=8192, IN=1, H=32, L=2.
//
// 512 blocks x 256 thr (4 waves); block owns 16 batch elements.
// Waves 0,1: layer 0 (hidden half wl) -- true-dependency path, s_setprio(1).
// Waves 2,3: layer 1, lagged one step. y-head MFMA alternates w2/w3.
//
// NEW (R20): ih/x-side MFMAs are PRECOMPUTED into P* accumulators in the
// post-barrier slack (while the B0 ds_read is in flight), so the per-step
// critical chain is ONE dependent MFMA (A_h x B0 + P*) instead of a 2-deep
// chain after a naked 120-cyc LDS read. Ledger (R12-R19): busy time is
// invariant ~110us; the 34% bubble is exposed latency -- this shaves the
// two largest serial components without adding work.
//
// Gate math (R13): merged-rcp combine, 5 trans/elem:
//   h' = [Nx*Nz - 2*Ez + (h-1)*Nx] * rcp(Nx*Nz);  hm = h-1 in registers.

#define S_LEN 256
#define B_SZ  8192
#define H_SZ  32
#define RS    40     // LDS row stride in shorts (80 B)

typedef __attribute__((ext_vector_type(8))) short short8;  // 8 bf16
typedef __attribute__((ext_vector_type(4))) float f32x4;   // MFMA C/D

#define MFMA(a, b, c) __builtin_amdgcn_mfma_f32_16x16x32_bf16(a, b, c, 0, 0, 0)

__device__ __forceinline__ unsigned short bf_rne1(float f) {
    union { float f; unsigned u; } x; x.f = f;
    unsigned u = x.u + 0x7fffu + ((x.u >> 16) & 1u);
    return (unsigned short)(u >> 16);
}

#if __has_builtin(__builtin_amdgcn_cvt_pk_bf16_f32)
typedef __bf16 bf16x2 __attribute__((ext_vector_type(2)));
__device__ __forceinline__ unsigned pk2(float a, float b) {
    union { bf16x2 v; unsigned u; } c;
    c.v = __builtin_amdgcn_cvt_pk_bf16_f32(a, b);
    return c.u;
}
#else
__device__ __forceinline__ unsigned pk2(float a, float b) {
    return (unsigned)bf_rne1(a) | ((unsigned)bf_rne1(b) << 16);
}
#endif

union Frag8 { short8 s8; unsigned u[4]; };

// Merged-rcp GRU combine: 3 exp2 + 2 rcp per element.
// Dr,Dz carry -log2e*(preact); Dn,Dxn carry 2log2e*(hh / ih parts of n).
// hm[r] = h-1 (updated in place). Returns packed bf16 pairs.
__device__ __forceinline__ uint2 gru_combine(const f32x4& Dr, const f32x4& Dz,
                                             const f32x4& Dn, const f32x4& Dxn,
                                             float* hm) {
    float v4[4];
#pragma unroll
    for (int r = 0; r < 4; ++r) {
        const float Er = __builtin_amdgcn_exp2f(Dr[r]);
        const float rg = __builtin_amdgcn_rcpf(1.0f + Er);           // r gate
        const float X  = __builtin_amdgcn_exp2f(fmaf(rg, Dn[r], Dxn[r]));
        const float Ez = __builtin_amdgcn_exp2f(Dz[r]);
        const float Nx = 1.0f + X;            // tanh denom
        const float Nz = 1.0f + Ez;           // z denom
        const float P  = Nx * Nz;
        float num = fmaf(-2.0f, Ez, P);       // Nx*Nz - 2*Ez
        num = fmaf(hm[r], Nx, num);           // + (h-1)*Nx
        const float v = num * __builtin_amdgcn_rcpf(P);
        hm[r] = v - 1.0f;
        v4[r] = v;
    }
    return make_uint2(pk2(v4[0], v4[1]), pk2(v4[2], v4[3]));
}

__global__ __launch_bounds__(256) void gru_xm(
    const float* __restrict__ x,      // (S,B,1)
    const float* __restrict__ h_in,   // (2,B,H)
    const float* __restrict__ W_ih0,  // (96,1)
    const float* __restrict__ W_hh0,  // (96,32)
    const float* __restrict__ b_ih0,  // (96)
    const float* __restrict__ b_hh0,  // (96)
    const float* __restrict__ W_ih1,  // (96,32)
    const float* __restrict__ W_hh1,  // (96,32)
    const float* __restrict__ b_ih1,  // (96)
    const float* __restrict__ b_hh1,  // (96)
    const float* __restrict__ W_out,  // (1,32)
    const float* __restrict__ b_out,  // (1)
    float* __restrict__ out)          // y (S*B) then h_state (2,B,H)
{
    __shared__ __align__(16) unsigned short sh0[2][16 * RS];  // h0 bf16
    __shared__ __align__(16) unsigned short sh1[2][16 * RS];  // h1 bf16
    __shared__ __align__(16) float sx[(S_LEN + 1) * 16];      // staged x (+pad)
    __shared__ __align__(16) float sy[S_LEN * 16];            // buffered y

    const int tid  = threadIdx.x;
    const int w    = tid >> 6;        // 0,1 -> layer 0; 2,3 -> layer 1
    const int lane = tid & 63;
    const int n    = lane & 15;       // batch col / A-row index
    const int q    = lane >> 4;       // quad
    const int base = blockIdx.x * 16;
    const int bn   = base + n;
    const int wl   = w & 1;           // hidden half within the layer

    // ---- stage x (coalesced float4, all waves) ----
    for (int s = tid; s < S_LEN * 4; s += 256) {
        const int t = s >> 2, c = s & 3;
        *(float4*)&sx[t * 16 + c * 4] = *(const float4*)&x[t * B_SZ + base + c * 4];
    }

    const float SRZ = -1.4426950408889634f;  // -log2(e)   (sigmoid gates)
    const float SN  =  2.8853900817779268f;  //  2*log2(e) (tanh gate)

    // ---- per-role persistent weights ----
    short8 A_h[3], A_i[3];                        // recurrent / (L1 ih | L0 x)
    f32x4  C_h[3], C_i3;
    f32x4  Pr, Pz, Pn;                            // precomputed ih/x accums
    short8 Awo = {0, 0, 0, 0, 0, 0, 0, 0};        // y head A-frag (w2,w3)
    short8 Bx  = {0, 0, 0, 0, 0, 0, 0, 0};        // x B-frag (w01), k=0 slot
    float  hm[4];                                  // own h half - 1, fp32

    if (w < 2) {
#pragma unroll
        for (int t = 0; t < 3; ++t) {
            const float sc = (t < 2) ? SRZ : SN;
            const int row = 32 * t + 16 * wl + n;
#pragma unroll
            for (int e = 0; e < 8; ++e)
                A_h[t][e] = (short)bf_rne1(W_hh0[row * H_SZ + q * 8 + e] * sc);
            // one-column x-weight fragment: k=0 only (q==0 && e==0)
#pragma unroll
            for (int e = 0; e < 8; ++e)
                A_i[t][e] = (q == 0 && e == 0)
                            ? (short)bf_rne1(W_ih0[row] * sc) : (short)0;
#pragma unroll
            for (int r = 0; r < 4; ++r) {
                const int g = 32 * t + 16 * wl + 4 * q + r;
                C_h[t][r] = (t < 2) ? SRZ * (b_ih0[g] + b_hh0[g])
                                    : SN * b_hh0[g];
                if (t == 2) C_i3[r] = SN * b_ih0[g];   // n-gate ih bias
            }
        }
#pragma unroll
        for (int r = 0; r < 4; ++r)
            hm[r] = h_in[bn * H_SZ + 16 * wl + 4 * q + r] - 1.0f;
    } else {
#pragma unroll
        for (int t = 0; t < 3; ++t) {
            const float sc = (t < 2) ? SRZ : SN;
            const int row = 32 * t + 16 * wl + n;
#pragma unroll
            for (int e = 0; e < 8; ++e) {
                A_h[t][e] = (short)bf_rne1(W_hh1[row * H_SZ + q * 8 + e] * sc);
                A_i[t][e] = (short)bf_rne1(W_ih1[row * H_SZ + q * 8 + e] * sc);
            }
#pragma unroll
            for (int r = 0; r < 4; ++r) {
                const int g = 32 * t + 16 * wl + 4 * q + r;
                C_h[t][r] = (t < 2) ? SRZ * (b_ih1[g] + b_hh1[g])
                                    : SN * b_hh1[g];
                if (t == 2) C_i3[r] = SN * b_ih1[g];
            }
        }
#pragma unroll
        for (int r = 0; r < 4; ++r)
            hm[r] = h_in[B_SZ * H_SZ + bn * H_SZ + 16 * wl + 4 * q + r] - 1.0f;
#pragma unroll
        for (int e = 0; e < 8; ++e)
            Awo[e] = (n == 0) ? (short)bf_rne1(W_out[q * 8 + e]) : (short)0;
    }
    const f32x4 Z4 = {0.f, 0.f, 0.f, 0.f};
    const float bout = b_out[0];

    // ---- initial B fragments (bf16 from h_in) ----
    short8 B0, B1;   // w01: B0 = h0(i-1). w23: B0 = h0(i-1), B1 = h1(i-2).
    {
        const float* hsrc = h_in + (size_t)(w >= 2) * B_SZ * H_SZ + bn * H_SZ + q * 8;
        Frag8 f;
        const float4 a = *(const float4*)&hsrc[0];
        const float4 b = *(const float4*)&hsrc[4];
        f.u[0] = pk2(a.x, a.y); f.u[1] = pk2(a.z, a.w);
        f.u[2] = pk2(b.x, b.y); f.u[3] = pk2(b.z, b.w);
        if (w < 2) B0 = f.s8; else B1 = f.s8;
    }

    const int wroff = n * RS + 16 * wl + 4 * q;   // b64 write (shorts)
    const int rdoff = n * RS + 8 * q;             // b128 read (shorts)

    __syncthreads();   // x staged

    // De-phase co-resident blocks (R16, neutral-but-free; kept).
    if ((blockIdx.x ^ (blockIdx.x >> 8)) & 1) __builtin_amdgcn_s_sleep(12);

    float xcur = sx[n];
    if (w < 2) __builtin_amdgcn_s_setprio(1);   // true-dep path issues first

    // ---- prologue P* for w01: x(0)-side accumulators ----
    if (w < 2) {
        Frag8 bxu; bxu.s8 = Bx; bxu.u[0] = pk2(xcur, xcur); Bx = bxu.s8;
        Pr = MFMA(A_i[0], Bx, C_h[0]);
        Pz = MFMA(A_i[1], Bx, C_h[1]);
        Pn = MFMA(A_i[2], Bx, C_i3);
    }

    // ================= iter 0 (peeled): w01 compute h0(0) =================
    if (w < 2) {
        f32x4 Dr = MFMA(A_h[0], B0, Pr);     // single dependent MFMA
        f32x4 Dz = MFMA(A_h[1], B0, Pz);
        f32x4 Dn = MFMA(A_h[2], B0, C_h[2]);
        *(uint2*)&sh0[0][wroff] = gru_combine(Dr, Dz, Dn, Pn, hm);
        xcur = sx[16 + n];   // x(1), pre-barrier
    }
    __syncthreads();
    // post-barrier-0: reads + P* precompute for the first loop iteration.
    B0 = *(const short8*)&sh0[0][rdoff];   // h0(0), in flight
    if (w < 2) {
        Frag8 bxu; bxu.s8 = Bx; bxu.u[0] = pk2(xcur, xcur); Bx = bxu.s8;
        Pr = MFMA(A_i[0], Bx, C_h[0]);     // x(1)-side, independent of B0
        Pz = MFMA(A_i[1], Bx, C_h[1]);
        Pn = MFMA(A_i[2], Bx, C_i3);
    } else {
        Pr = MFMA(A_i[0], B0, C_h[0]);     // ih-side from h0(0)
        Pz = MFMA(A_i[1], B0, C_h[1]);
        Pn = MFMA(A_i[2], B0, C_i3);
    }

    // ================= hot loop i = 1 .. S-1 ===============================
#pragma unroll 2
    for (int i = 1; i < S_LEN; ++i) {
        const int buf = i & 1;
        if (w < 2) {
            // h0(i): one dependent MFMA per gate (P* holds bias + x-side).
            f32x4 Dr = MFMA(A_h[0], B0, Pr);
            f32x4 Dz = MFMA(A_h[1], B0, Pz);
            f32x4 Dn = MFMA(A_h[2], B0, C_h[2]);
            *(uint2*)&sh0[buf][wroff] = gru_combine(Dr, Dz, Dn, Pn, hm);
            xcur = sx[(i + 1) * 16 + n];   // prefetch, pre-barrier
        } else {
            // h1(i-1): B1 = h1(i-2) (read last iter), P* from h0(i-1).
            f32x4 Gr = MFMA(A_h[0], B1, Pr);
            f32x4 Gz = MFMA(A_h[1], B1, Pz);
            f32x4 Un = MFMA(A_h[2], B1, C_h[2]);
            *(uint2*)&sh1[buf][wroff] = gru_combine(Gr, Gz, Un, Pn, hm);
        }

        __syncthreads();   // publish h0(i) / h1(i-1)

        if (w < 2) {
            B0 = *(const short8*)&sh0[buf][rdoff];          // h0(i), in flight
            // fill the read shadow: Bx pack + x-side MFMAs (B0-independent)
            Frag8 bxu; bxu.s8 = Bx; bxu.u[0] = pk2(xcur, xcur); Bx = bxu.s8;
            Pr = MFMA(A_i[0], Bx, C_h[0]);
            Pz = MFMA(A_i[1], Bx, C_h[1]);
            Pn = MFMA(A_i[2], Bx, C_i3);
        } else {
            B0 = *(const short8*)&sh0[buf][rdoff];          // h0(i)
            B1 = *(const short8*)&sh1[buf][rdoff];          // h1(i-1)
            if (w == 2 + ((i - 1) & 1)) {
                // y(i-1) = W_out . h1(i-1): one MFMA, row 0 = result.
                const f32x4 yD = MFMA(Awo, B1, Z4);
                if (lane < 16) sy[(i - 1) * 16 + n] = yD[0];
            }
            Pr = MFMA(A_i[0], B0, C_h[0]);   // ih-side from fresh h0(i)
            Pz = MFMA(A_i[1], B0, C_h[1]);
            Pn = MFMA(A_i[2], B0, C_i3);
        }
    }

    // ================= iter S (peeled): w23 compute h1(S-1) ================
    if (w >= 2) {
        f32x4 Gr = MFMA(A_h[0], B1, Pr);
        f32x4 Gz = MFMA(A_h[1], B1, Pz);
        f32x4 Un = MFMA(A_h[2], B1, C_h[2]);
        *(uint2*)&sh1[0][wroff] = gru_combine(Gr, Gz, Un, Pn, hm);
    }
    __syncthreads();
    if (w == 2 + ((S_LEN - 1) & 1)) {
        B1 = *(const short8*)&sh1[0][rdoff];               // h1(S-1)
        const f32x4 yD = MFMA(Awo, B1, Z4);
        if (lane < 16) sy[(S_LEN - 1) * 16 + n] = yD[0];
    }
    __syncthreads();   // sy complete

    // ---- flush y (coalesced float4 + bias) ----
    for (int s = tid; s < S_LEN * 4; s += 256) {
        const int t = s >> 2, c = s & 3;
        const float4 a = *(const float4*)&sy[t * 16 + c * 4];
        *(float4*)&out[t * B_SZ + base + c * 4] =
            make_float4(a.x + bout, a.y + bout, a.z + bout, a.w + bout);
    }

    // ---- final h_state: out = y (S*B) ++ h0 (B*H) ++ h1 (B*H) ----
    const size_t hoff = (size_t)S_LEN * B_SZ + (size_t)(w >= 2) * B_SZ * H_SZ;
    *(float4*)&out[hoff + bn * H_SZ + 16 * wl + 4 * q] =
        make_float4(hm[0] + 1.0f, hm[1] + 1.0f, hm[2] + 1.0f, hm[3] + 1.0f);
}

extern "C" void kernel_launch(void* const* d_in, const int* in_sizes, int n_in,
                              void* d_out, int out_size, void* d_ws, size_t ws_size,
                              hipStream_t stream) {
    (void)in_sizes; (void)n_in; (void)out_size; (void)d_ws; (void)ws_size;
    const float* x     = (const float*)d_in[0];
    const float* h_in  = (const float*)d_in[1];
    const float* W_ih0 = (const float*)d_in[2];
    const float* W_hh0 = (const float*)d_in[3];
    const float* b_ih0 = (const float*)d_in[4];
    const float* b_hh0 = (const float*)d_in[5];
    const float* W_ih1 = (const float*)d_in[6];
    const float* W_hh1 = (const float*)d_in[7];
    const float* b_ih1 = (const float*)d_in[8];
    const float* b_hh1 = (const float*)d_in[9];
    const float* W_out = (const float*)d_in[10];
    const float* b_out = (const float*)d_in[11];

    dim3 grid(B_SZ / 16);   // 512 blocks x 4 waves = 2048 waves (2/SIMD)
    dim3 block(256);
    gru_xm<<<grid, block, 0, stream>>>(x, h_in, W_ih0, W_hh0, b_ih0, b_hh0,
                                       W_ih1, W_hh1, b_ih1, b_hh1,
                                       W_out, b_out, (float*)d_out);
}

// Round 9
// 232.558 us; speedup vs baseline: 1.4960x; 1.0229x over previous
//
#include <hip/hip_runtime.h>

// Fused 2-layer GRU, round 21: R16 base + block-parity ROLE ROTATION.
// S=256, B=8192, IN=1, H=32, L=2.
//
// 512 blocks x 256 thr (4 waves); block owns 16 batch elements.
// Role lw = (w + 2*(blockIdx&1)) & 3: even blocks {w0,w1}=L0,{w2,w3}=L1;
// odd blocks rotated. HW maps wave k -> SIMD k%4, and 2 blocks co-reside
// per CU, so each SIMD now hosts ONE L0-wave + ONE L1-wave instead of two
// same-role waves. Different roles = different instruction mixes & stall
// phases -> the ~535 cyc/iter of correlated same-role micro-stalls (immune
// to R13/R15/R16/R17/R19/R20 levers; busy-time invariant ~110us) should
// interleave. lw==0/1: layer-0 halves (true-dep path, setprio 1);
// lw==2/3: layer-1 lagged one step, y-head alternates.
//
// Gate math (R13): merged-rcp combine, 5 trans/elem:
//   h' = [Nx*Nz - 2*Ez + (h-1)*Nx] * rcp(Nx*Nz);  hm = h-1 in registers.

#define S_LEN 256
#define B_SZ  8192
#define H_SZ  32
#define RS    40     // LDS row stride in shorts (80 B)

typedef __attribute__((ext_vector_type(8))) short short8;  // 8 bf16
typedef __attribute__((ext_vector_type(4))) float f32x4;   // MFMA C/D

#define MFMA(a, b, c) __builtin_amdgcn_mfma_f32_16x16x32_bf16(a, b, c, 0, 0, 0)

__device__ __forceinline__ unsigned short bf_rne1(float f) {
    union { float f; unsigned u; } x; x.f = f;
    unsigned u = x.u + 0x7fffu + ((x.u >> 16) & 1u);
    return (unsigned short)(u >> 16);
}

#if __has_builtin(__builtin_amdgcn_cvt_pk_bf16_f32)
typedef __bf16 bf16x2 __attribute__((ext_vector_type(2)));
__device__ __forceinline__ unsigned pk2(float a, float b) {
    union { bf16x2 v; unsigned u; } c;
    c.v = __builtin_amdgcn_cvt_pk_bf16_f32(a, b);
    return c.u;
}
#else
__device__ __forceinline__ unsigned pk2(float a, float b) {
    return (unsigned)bf_rne1(a) | ((unsigned)bf_rne1(b) << 16);
}
#endif

union Frag8 { short8 s8; unsigned u[4]; };

// Merged-rcp GRU combine: 3 exp2 + 2 rcp per element.
// Dr,Dz carry -log2e*(preact); Dn,Dxn carry 2log2e*(hh / ih parts of n).
// hm[r] = h-1 (updated in place). Returns packed bf16 pairs.
__device__ __forceinline__ uint2 gru_combine(const f32x4& Dr, const f32x4& Dz,
                                             const f32x4& Dn, const f32x4& Dxn,
                                             float* hm) {
    float v4[4];
#pragma unroll
    for (int r = 0; r < 4; ++r) {
        const float Er = __builtin_amdgcn_exp2f(Dr[r]);
        const float rg = __builtin_amdgcn_rcpf(1.0f + Er);           // r gate
        const float X  = __builtin_amdgcn_exp2f(fmaf(rg, Dn[r], Dxn[r]));
        const float Ez = __builtin_amdgcn_exp2f(Dz[r]);
        const float Nx = 1.0f + X;            // tanh denom
        const float Nz = 1.0f + Ez;           // z denom
        const float P  = Nx * Nz;
        float num = fmaf(-2.0f, Ez, P);       // Nx*Nz - 2*Ez
        num = fmaf(hm[r], Nx, num);           // + (h-1)*Nx
        const float v = num * __builtin_amdgcn_rcpf(P);
        hm[r] = v - 1.0f;
        v4[r] = v;
    }
    return make_uint2(pk2(v4[0], v4[1]), pk2(v4[2], v4[3]));
}

__global__ __launch_bounds__(256) void gru_xm(
    const float* __restrict__ x,      // (S,B,1)
    const float* __restrict__ h_in,   // (2,B,H)
    const float* __restrict__ W_ih0,  // (96,1)
    const float* __restrict__ W_hh0,  // (96,32)
    const float* __restrict__ b_ih0,  // (96)
    const float* __restrict__ b_hh0,  // (96)
    const float* __restrict__ W_ih1,  // (96,32)
    const float* __restrict__ W_hh1,  // (96,32)
    const float* __restrict__ b_ih1,  // (96)
    const float* __restrict__ b_hh1,  // (96)
    const float* __restrict__ W_out,  // (1,32)
    const float* __restrict__ b_out,  // (1)
    float* __restrict__ out)          // y (S*B) then h_state (2,B,H)
{
    __shared__ __align__(16) unsigned short sh0[2][16 * RS];  // h0 bf16
    __shared__ __align__(16) unsigned short sh1[2][16 * RS];  // h1 bf16
    __shared__ __align__(16) float sx[(S_LEN + 1) * 16];      // staged x (+pad)
    __shared__ __align__(16) float sy[S_LEN * 16];            // buffered y

    const int tid  = threadIdx.x;
    // Role rotation: odd blocks swap layer assignment of wave pairs so each
    // SIMD (wave k -> SIMD k%4, 2 blocks/CU) hosts one L0 and one L1 wave.
    const int lw   = ((tid >> 6) + ((blockIdx.x & 1) << 1)) & 3;
    const int lane = tid & 63;
    const int n    = lane & 15;       // batch col / A-row index
    const int q    = lane >> 4;       // quad
    const int base = blockIdx.x * 16;
    const int bn   = base + n;
    const int wl   = lw & 1;          // hidden half within the layer

    // ---- stage x (coalesced float4, all waves) ----
    for (int s = tid; s < S_LEN * 4; s += 256) {
        const int t = s >> 2, c = s & 3;
        *(float4*)&sx[t * 16 + c * 4] = *(const float4*)&x[t * B_SZ + base + c * 4];
    }

    const float SRZ = -1.4426950408889634f;  // -log2(e)   (sigmoid gates)
    const float SN  =  2.8853900817779268f;  //  2*log2(e) (tanh gate)

    // ---- per-role persistent weights ----
    short8 A_h[3], A_i[3];                        // recurrent / (L1 ih | L0 x)
    f32x4  C_h[3], C_i3;
    short8 Awo = {0, 0, 0, 0, 0, 0, 0, 0};        // y head A-frag (lw2,lw3)
    short8 Bx  = {0, 0, 0, 0, 0, 0, 0, 0};        // x B-frag (lw01), k=0 slot
    float  hm[4];                                  // own h half - 1, fp32

    if (lw < 2) {
#pragma unroll
        for (int t = 0; t < 3; ++t) {
            const float sc = (t < 2) ? SRZ : SN;
            const int row = 32 * t + 16 * wl + n;
#pragma unroll
            for (int e = 0; e < 8; ++e)
                A_h[t][e] = (short)bf_rne1(W_hh0[row * H_SZ + q * 8 + e] * sc);
            // one-column x-weight fragment: k=0 only (q==0 && e==0)
#pragma unroll
            for (int e = 0; e < 8; ++e)
                A_i[t][e] = (q == 0 && e == 0)
                            ? (short)bf_rne1(W_ih0[row] * sc) : (short)0;
#pragma unroll
            for (int r = 0; r < 4; ++r) {
                const int g = 32 * t + 16 * wl + 4 * q + r;
                C_h[t][r] = (t < 2) ? SRZ * (b_ih0[g] + b_hh0[g])
                                    : SN * b_hh0[g];
                if (t == 2) C_i3[r] = SN * b_ih0[g];   // n-gate ih bias
            }
        }
#pragma unroll
        for (int r = 0; r < 4; ++r)
            hm[r] = h_in[bn * H_SZ + 16 * wl + 4 * q + r] - 1.0f;
    } else {
#pragma unroll
        for (int t = 0; t < 3; ++t) {
            const float sc = (t < 2) ? SRZ : SN;
            const int row = 32 * t + 16 * wl + n;
#pragma unroll
            for (int e = 0; e < 8; ++e) {
                A_h[t][e] = (short)bf_rne1(W_hh1[row * H_SZ + q * 8 + e] * sc);
                A_i[t][e] = (short)bf_rne1(W_ih1[row * H_SZ + q * 8 + e] * sc);
            }
#pragma unroll
            for (int r = 0; r < 4; ++r) {
                const int g = 32 * t + 16 * wl + 4 * q + r;
                C_h[t][r] = (t < 2) ? SRZ * (b_ih1[g] + b_hh1[g])
                                    : SN * b_hh1[g];
                if (t == 2) C_i3[r] = SN * b_ih1[g];
            }
        }
#pragma unroll
        for (int r = 0; r < 4; ++r)
            hm[r] = h_in[B_SZ * H_SZ + bn * H_SZ + 16 * wl + 4 * q + r] - 1.0f;
#pragma unroll
        for (int e = 0; e < 8; ++e)
            Awo[e] = (n == 0) ? (short)bf_rne1(W_out[q * 8 + e]) : (short)0;
    }
    const f32x4 Z4 = {0.f, 0.f, 0.f, 0.f};
    const float bout = b_out[0];

    // ---- initial B fragments (bf16 from h_in) ----
    short8 B0, B1;   // lw01: B0 = h0(i-1). lw23: B0 = h0(i-1), B1 = h1(i-2).
    {
        const float* hsrc = h_in + (size_t)(lw >= 2) * B_SZ * H_SZ + bn * H_SZ + q * 8;
        Frag8 f;
        const float4 a = *(const float4*)&hsrc[0];
        const float4 b = *(const float4*)&hsrc[4];
        f.u[0] = pk2(a.x, a.y); f.u[1] = pk2(a.z, a.w);
        f.u[2] = pk2(b.x, b.y); f.u[3] = pk2(b.z, b.w);
        if (lw < 2) B0 = f.s8; else B1 = f.s8;
    }

    const int wroff = n * RS + 16 * wl + 4 * q;   // b64 write (shorts)
    const int rdoff = n * RS + 8 * q;             // b128 read (shorts)

    __syncthreads();   // x staged

    float xcur = sx[n];
    if (lw < 2) __builtin_amdgcn_s_setprio(1);   // true-dep path issues first

    // ================= iter 0 (peeled): lw01 compute h0(0) =================
    if (lw < 2) {
        Frag8 bxu; bxu.s8 = Bx; bxu.u[0] = pk2(xcur, xcur); Bx = bxu.s8;
        f32x4 Dr = MFMA(A_h[0], B0, C_h[0]);  Dr = MFMA(A_i[0], Bx, Dr);
        f32x4 Dz = MFMA(A_h[1], B0, C_h[1]);  Dz = MFMA(A_i[1], Bx, Dz);
        f32x4 Dn = MFMA(A_h[2], B0, C_h[2]);
        f32x4 Dxn = MFMA(A_i[2], Bx, C_i3);
        *(uint2*)&sh0[0][wroff] = gru_combine(Dr, Dz, Dn, Dxn, hm);
        xcur = sx[16 + n];   // x(1)
    }
    __syncthreads();
    B0 = *(const short8*)&sh0[0][rdoff];   // h0(0) for all waves

    // ================= hot loop i = 1 .. S-1 (no predication) ==============
#pragma unroll 2
    for (int i = 1; i < S_LEN; ++i) {
        const int buf = i & 1;
        if (lw < 2) {
            // h0(i) from B0 = h0(i-1): the true-dependency path.
            Frag8 bxu; bxu.s8 = Bx; bxu.u[0] = pk2(xcur, xcur); Bx = bxu.s8;
            f32x4 Dr = MFMA(A_h[0], B0, C_h[0]);  Dr = MFMA(A_i[0], Bx, Dr);
            f32x4 Dz = MFMA(A_h[1], B0, C_h[1]);  Dz = MFMA(A_i[1], Bx, Dz);
            f32x4 Dn = MFMA(A_h[2], B0, C_h[2]);
            f32x4 Dxn = MFMA(A_i[2], Bx, C_i3);
            *(uint2*)&sh0[buf][wroff] = gru_combine(Dr, Dz, Dn, Dxn, hm);
            xcur = sx[(i + 1) * 16 + n];   // read-only prefetch, pre-barrier
        } else {
            // h1(i-1) from B1 = h1(i-2), B0 = h0(i-1): prefetched last iter.
            // ih-side chained onto hh-side accumulators (no combine-adds).
            f32x4 Gr = MFMA(A_h[0], B1, C_h[0]);  Gr = MFMA(A_i[0], B0, Gr);
            f32x4 Gz = MFMA(A_h[1], B1, C_h[1]);  Gz = MFMA(A_i[1], B0, Gz);
            f32x4 Un = MFMA(A_h[2], B1, C_h[2]);
            f32x4 Vn = MFMA(A_i[2], B0, C_i3);
            *(uint2*)&sh1[buf][wroff] = gru_combine(Gr, Gz, Un, Vn, hm);
        }

        __syncthreads();   // lgkm-only drain

        if (lw < 2) {
            B0 = *(const short8*)&sh0[buf][rdoff];          // h0(i)
        } else {
            B0 = *(const short8*)&sh0[buf][rdoff];          // h0(i)
            B1 = *(const short8*)&sh1[buf][rdoff];          // h1(i-1)
            if (lw == 2 + ((i - 1) & 1)) {
                // y(i-1) = W_out . h1(i-1): one MFMA, row 0 = result.
                // Alternates lw2/lw3 so neither wave straggles every iter.
                const f32x4 yD = MFMA(Awo, B1, Z4);
                if (lane < 16) sy[(i - 1) * 16 + n] = yD[0];
            }
        }
    }

    // ================= iter S (peeled): lw23 compute h1(S-1) ================
    if (lw >= 2) {
        f32x4 Gr = MFMA(A_h[0], B1, C_h[0]);  Gr = MFMA(A_i[0], B0, Gr);
        f32x4 Gz = MFMA(A_h[1], B1, C_h[1]);  Gz = MFMA(A_i[1], B0, Gz);
        f32x4 Un = MFMA(A_h[2], B1, C_h[2]);
        f32x4 Vn = MFMA(A_i[2], B0, C_i3);
        *(uint2*)&sh1[0][wroff] = gru_combine(Gr, Gz, Un, Vn, hm);
    }
    __syncthreads();
    if (lw == 2 + ((S_LEN - 1) & 1)) {
        B1 = *(const short8*)&sh1[0][rdoff];               // h1(S-1)
        const f32x4 yD = MFMA(Awo, B1, Z4);
        if (lane < 16) sy[(S_LEN - 1) * 16 + n] = yD[0];
    }
    __syncthreads();   // sy complete

    // ---- flush y (coalesced float4 + bias) ----
    for (int s = tid; s < S_LEN * 4; s += 256) {
        const int t = s >> 2, c = s & 3;
        const float4 a = *(const float4*)&sy[t * 16 + c * 4];
        *(float4*)&out[t * B_SZ + base + c * 4] =
            make_float4(a.x + bout, a.y + bout, a.z + bout, a.w + bout);
    }

    // ---- final h_state: out = y (S*B) ++ h0 (B*H) ++ h1 (B*H) ----
    const size_t hoff = (size_t)S_LEN * B_SZ + (size_t)(lw >= 2) * B_SZ * H_SZ;
    *(float4*)&out[hoff + bn * H_SZ + 16 * wl + 4 * q] =
        make_float4(hm[0] + 1.0f, hm[1] + 1.0f, hm[2] + 1.0f, hm[3] + 1.0f);
}

extern "C" void kernel_launch(void* const* d_in, const int* in_sizes, int n_in,
                              void* d_out, int out_size, void* d_ws, size_t ws_size,
                              hipStream_t stream) {
    (void)in_sizes; (void)n_in; (void)out_size; (void)d_ws; (void)ws_size;
    const float* x     = (const float*)d_in[0];
    const float* h_in  = (const float*)d_in[1];
    const float* W_ih0 = (const float*)d_in[2];
    const float* W_hh0 = (const float*)d_in[3];
    const float* b_ih0 = (const float*)d_in[4];
    const float* b_hh0 = (const float*)d_in[5];
    const float* W_ih1 = (const float*)d_in[6];
    const float* W_hh1 = (const float*)d_in[7];
    const float* b_ih1 = (const float*)d_in[8];
    const float* b_hh1 = (const float*)d_in[9];
    const float* W_out = (const float*)d_in[10];
    const float* b_out = (const float*)d_in[11];

    dim3 grid(B_SZ / 16);   // 512 blocks x 4 waves = 2048 waves (2/SIMD)
    dim3 block(256);
    gru_xm<<<grid, block, 0, stream>>>(x, h_in, W_ih0, W_hh0, b_ih0, b_hh0,
                                       W_ih1, W_hh1, b_ih1, b_hh1,
                                       W_out, b_out, (float*)d_out);
}